// Round 4
// baseline (458.380 us; speedup 1.0000x reference)
//
#include <hip/hip_runtime.h>
#include <hip/hip_bf16.h>

#define NGRAPH 4096
#define MAXN 384   // max nodes/graph; Binomial(5e5,1/4096) max ~165, 384 is >20 sigma

typedef __attribute__((ext_vector_type(8))) short s16x8;
typedef __attribute__((ext_vector_type(4))) float f32x4;

__device__ inline short f2bf(float f) {
  unsigned u = __float_as_uint(f);
  unsigned r = u + 0x7fffu + ((u >> 16) & 1u);
  return (short)(r >> 16);
}

// Prepack W1 (256x128 fp32, row-major) into bf16 MFMA B-fragment order.
// Fragment f = kt*8 + ct (kt,ct in 0..7). Lane l supplies B[k][c] for
// k = kt*32 + (l>>4)*8 + e (e=0..7), c = ct*16 + (l&15).
__global__ void prepack_w1(const float* __restrict__ W1, s16x8* __restrict__ w1p) {
  int t = blockIdx.x * 256 + threadIdx.x;   // 4096 threads total
  int f = t >> 6, l = t & 63;
  int kt = f >> 3, ct = f & 7;
  int k0 = kt * 32 + ((l >> 4) * 8);
  int c  = ct * 16 + (l & 15);
  s16x8 v;
  #pragma unroll
  for (int e = 0; e < 8; ++e) v[e] = f2bf(W1[(k0 + e) * 128 + c]);
  w1p[f * 64 + l] = v;
}

__device__ inline long long getb(const void* b, int i, int is64) {
  if (is64) return ((const long long*)b)[i];
  return (long long)((const int*)b)[i];
}

__device__ inline int lowb(const void* b, int n, long long v, int is64) {
  int lo = 0, hi = n;
  while (lo < hi) {
    int mid = (lo + hi) >> 1;
    if (getb(b, mid, is64) < v) lo = mid + 1; else hi = mid;
  }
  return lo;
}

// One-time: offs[g] = lower_bound(batch, g). 4097 independent searches,
// latency hidden by TLP; batch (2-4 MB) L2/L3-resident after first touches.
__global__ void seg_offsets(const void* __restrict__ batch, int* __restrict__ offs, int N) {
  int g = blockIdx.x * 256 + threadIdx.x;
  // int64 vs int32 materialization probe: an odd 32-bit word index has a zero
  // high word under int64 (values < 2^31), a near-max sorted id under int32.
  int probe = ((N & 1) == 0) ? (N - 1) : (N - 2);
  const int is64 = (((const int*)batch)[probe] == 0) ? 1 : 0;
  if (g <= NGRAPH) offs[g] = lowb(batch, N, (long long)g, is64);
}

__device__ inline float fast_tanh(float v) {
  v = fminf(fmaxf(v, -15.f), 15.f);
  float e = __expf(2.f * v);
  return __fdividef(e - 1.f, e + 1.f);
}

// One block per graph, 256 threads (4 waves). Three phases (R1 structure):
//  1) gate scores via MFMA: wave-pair owns a 16-node tile, colhalf owns 64 of
//     128 hidden cols; B-fragments loaded inline from L2-resident w1p (keeps
//     VGPR demand ~70 -> genuinely 4 blocks/CU under launch_bounds(256,4)).
//  2) block softmax over spart (LDS).
//  3) pooled[g][tid] = sum_n w_n * x[s+n][tid] (rows L2/L3-hot from phase 1).
__global__ __launch_bounds__(256, 4)
void attnpool(const float* __restrict__ x, const int* __restrict__ offs,
              const float* __restrict__ b1, const float* __restrict__ W2,
              const float* __restrict__ b2p, const s16x8* __restrict__ w1p,
              float* __restrict__ pooled, float* __restrict__ wout, int N)
{
  __shared__ float spart[2][MAXN];
  __shared__ float sred[8];

  const int g = blockIdx.x;
  const int tid = threadIdx.x;
  const int w = tid >> 6, l = tid & 63;
  const int colhalf = w & 1;            // waves 0,2 -> cols 0..63; 1,3 -> 64..127
  const int l15 = l & 15, lg = l >> 4;

  const int s = offs[g];
  const int cnt = min(offs[g + 1] - s, MAXN);   // clamp: never-taken safety net

  float b1v[4], w2v[4];
  #pragma unroll
  for (int ct = 0; ct < 4; ++ct) {
    int c = colhalf * 64 + ct * 16 + l15;
    b1v[ct] = b1[c];
    w2v[ct] = W2[c];
  }
  const float b2s = b2p[0];

  // ---- Phase 1: gate scores via MFMA (16-node tiles; wave pair per tile) ----
  const int tiles = (cnt + 15) >> 4;
  for (int t = (w >> 1); t < tiles; t += 2) {
    const int tb = t * 16;
    int row = s + tb + l15;
    if (row >= N) row = N - 1;          // pad rows: garbage, discarded below
    const float* xp = x + (size_t)row * 256 + lg * 8;
    f32x4 acc0 = {0.f,0.f,0.f,0.f}, acc1 = {0.f,0.f,0.f,0.f};
    f32x4 acc2 = {0.f,0.f,0.f,0.f}, acc3 = {0.f,0.f,0.f,0.f};
    #pragma unroll
    for (int kt = 0; kt < 8; ++kt) {
      float4 xa = *(const float4*)(xp + kt * 32);
      float4 xb = *(const float4*)(xp + kt * 32 + 4);
      const s16x8* wb = w1p + (kt * 8 + colhalf * 4) * 64 + l;   // L2-resident
      s16x8 bf0 = wb[0], bf1 = wb[64], bf2 = wb[128], bf3 = wb[192];
      s16x8 a;
      a[0] = f2bf(xa.x); a[1] = f2bf(xa.y); a[2] = f2bf(xa.z); a[3] = f2bf(xa.w);
      a[4] = f2bf(xb.x); a[5] = f2bf(xb.y); a[6] = f2bf(xb.z); a[7] = f2bf(xb.w);
      acc0 = __builtin_amdgcn_mfma_f32_16x16x32_bf16(a, bf0, acc0, 0, 0, 0);
      acc1 = __builtin_amdgcn_mfma_f32_16x16x32_bf16(a, bf1, acc1, 0, 0, 0);
      acc2 = __builtin_amdgcn_mfma_f32_16x16x32_bf16(a, bf2, acc2, 0, 0, 0);
      acc3 = __builtin_amdgcn_mfma_f32_16x16x32_bf16(a, bf3, acc3, 0, 0, 0);
    }
    // h = tanh(acc + b1); partial score = sum h*W2 over this wave's 64 cols.
    // D layout: node-in-tile = 4*lg + r, hidden-col = ct*16 + l15.
    float part[4];
    #pragma unroll
    for (int r = 0; r < 4; ++r) {
      part[r] = colhalf ? 0.f : b2s;
      part[r] += fast_tanh(acc0[r] + b1v[0]) * w2v[0];
      part[r] += fast_tanh(acc1[r] + b1v[1]) * w2v[1];
      part[r] += fast_tanh(acc2[r] + b1v[2]) * w2v[2];
      part[r] += fast_tanh(acc3[r] + b1v[3]) * w2v[3];
    }
    #pragma unroll
    for (int m = 1; m <= 8; m <<= 1) {
      #pragma unroll
      for (int r = 0; r < 4; ++r) part[r] += __shfl_xor(part[r], m, 64);
    }
    if (l15 == 0) {
      #pragma unroll
      for (int r = 0; r < 4; ++r) {
        int nl = tb + lg * 4 + r;
        if (nl < cnt) spart[colhalf][nl] = part[r];
      }
    }
  }
  __syncthreads();

  if (cnt > 0) {
    // ---- Phase 2: segment softmax (deterministic, no atomics) ----
    float lmax = -1e30f;
    for (int i = tid; i < cnt; i += 256) {
      float sc = spart[0][i] + spart[1][i];
      spart[0][i] = sc;
      lmax = fmaxf(lmax, sc);
    }
    #pragma unroll
    for (int m = 1; m <= 32; m <<= 1) lmax = fmaxf(lmax, __shfl_xor(lmax, m, 64));
    if (l == 0) sred[w] = lmax;
    __syncthreads();
    const float gmax = fmaxf(fmaxf(sred[0], sred[1]), fmaxf(sred[2], sred[3]));
    float lsum = 0.f;
    for (int i = tid; i < cnt; i += 256) {
      float ev = __expf(spart[0][i] - gmax);
      spart[0][i] = ev;
      lsum += ev;
    }
    #pragma unroll
    for (int m = 1; m <= 32; m <<= 1) lsum += __shfl_xor(lsum, m, 64);
    if (l == 0) sred[4 + w] = lsum;
    __syncthreads();
    const float inv = 1.f / (sred[4] + sred[5] + sred[6] + sred[7]);
    for (int i = tid; i < cnt; i += 256) {
      float wt = spart[0][i] * inv;
      spart[0][i] = wt;
      wout[s + i] = wt;
    }
    __syncthreads();

    // ---- Phase 3: pooled[g][col] = sum_n w_n * x[s+n][col], col = tid ----
    float pacc = 0.f;
    const float* xg = x + (size_t)s * 256 + tid;
    int n = 0;
    for (; n + 8 <= cnt; n += 8) {
      float wv[8], xv[8];
      #pragma unroll
      for (int u = 0; u < 8; ++u) {
        wv[u] = spart[0][n + u];
        xv[u] = xg[(size_t)(n + u) * 256];
      }
      #pragma unroll
      for (int u = 0; u < 8; ++u) pacc += wv[u] * xv[u];
    }
    for (; n < cnt; ++n) pacc += spart[0][n] * xg[(size_t)n * 256];
    pooled[(size_t)g * 256 + tid] = pacc;
  } else {
    pooled[(size_t)g * 256 + tid] = 0.f;   // empty segment -> zeros (ref guard)
  }
}

extern "C" void kernel_launch(void* const* d_in, const int* in_sizes, int n_in,
                              void* d_out, int out_size, void* d_ws, size_t ws_size,
                              hipStream_t stream) {
  const float* x     = (const float*)d_in[0];
  const void*  batch = d_in[1];
  const float* W1    = (const float*)d_in[2];
  const float* b1    = (const float*)d_in[3];
  const float* W2    = (const float*)d_in[4];
  const float* b2    = (const float*)d_in[5];
  const int N = in_sizes[0] / 256;

  float* pooled = (float*)d_out;
  float* wout   = (float*)d_out + (size_t)NGRAPH * 256;
  s16x8* w1p    = (s16x8*)d_ws;                       // 64 KB
  int*   offs   = (int*)((char*)d_ws + 64 * 1024);    // 4097 * 4 B

  prepack_w1<<<16, 256, 0, stream>>>(W1, w1p);
  seg_offsets<<<17, 256, 0, stream>>>(batch, offs, N);
  attnpool<<<NGRAPH, 256, 0, stream>>>(x, offs, b1, W2, b2, w1p, pooled, wout, N);
}

// Round 5
// 295.804 us; speedup vs baseline: 1.5496x; 1.5496x over previous
//
#include <hip/hip_runtime.h>
#include <hip/hip_bf16.h>

#define NGRAPH 4096
#define MAXN 384   // max nodes/graph; Binomial(5e5,1/4096) max ~165, 384 is >20 sigma

typedef __attribute__((ext_vector_type(8))) short s16x8;
typedef __attribute__((ext_vector_type(4))) float f32x4;

__device__ inline short f2bf(float f) {
  unsigned u = __float_as_uint(f);
  unsigned r = u + 0x7fffu + ((u >> 16) & 1u);
  return (short)(r >> 16);
}

// Prepack W1 (256x128 fp32, row-major) into bf16 MFMA B-fragment order.
// Fragment f = kt*8 + ct (kt,ct in 0..7). Lane l supplies B[k][c] for
// k = kt*32 + (l>>4)*8 + e (e=0..7), c = ct*16 + (l&15).
__global__ void prepack_w1(const float* __restrict__ W1, s16x8* __restrict__ w1p) {
  int t = blockIdx.x * 256 + threadIdx.x;   // 4096 threads total
  int f = t >> 6, l = t & 63;
  int kt = f >> 3, ct = f & 7;
  int k0 = kt * 32 + ((l >> 4) * 8);
  int c  = ct * 16 + (l & 15);
  s16x8 v;
  #pragma unroll
  for (int e = 0; e < 8; ++e) v[e] = f2bf(W1[(k0 + e) * 128 + c]);
  w1p[f * 64 + l] = v;
}

__device__ inline long long getb(const void* b, int i, int is64) {
  if (is64) return ((const long long*)b)[i];
  return (long long)((const int*)b)[i];
}

__device__ inline int lowb(const void* b, int n, long long v, int is64) {
  int lo = 0, hi = n;
  while (lo < hi) {
    int mid = (lo + hi) >> 1;
    if (getb(b, mid, is64) < v) lo = mid + 1; else hi = mid;
  }
  return lo;
}

// One-time: offs[g] = lower_bound(batch, g). 4097 independent searches,
// latency hidden by TLP; batch (2-4 MB) L2/L3-resident after first touches.
__global__ void seg_offsets(const void* __restrict__ batch, int* __restrict__ offs, int N) {
  int g = blockIdx.x * 256 + threadIdx.x;
  // int64 vs int32 materialization probe: an odd 32-bit word index has a zero
  // high word under int64 (values < 2^31), a near-max sorted id under int32.
  int probe = ((N & 1) == 0) ? (N - 1) : (N - 2);
  const int is64 = (((const int*)batch)[probe] == 0) ? 1 : 0;
  if (g <= NGRAPH) offs[g] = lowb(batch, N, (long long)g, is64);
}

__device__ inline float fast_tanh(float v) {
  v = fminf(fmaxf(v, -15.f), 15.f);
  float e = __expf(2.f * v);
  return __fdividef(e - 1.f, e + 1.f);
}

// Kernel A: gate scores for ALL nodes, node-parallel streaming (no graph
// logic). Block = 256 threads = 2 wave-pairs; block handles 64 nodes as
// 4 16-node MFMA tiles (wave-pair wp does tiles wp, wp+2; colhalf = w&1 owns
// 64 of 128 hidden cols). Raw scores written to scr[] (the wout region,
// overwritten by softmax_pool later).
__global__ __launch_bounds__(256, 3)
void gate_scores(const float* __restrict__ x, const float* __restrict__ b1,
                 const float* __restrict__ W2, const float* __restrict__ b2p,
                 const s16x8* __restrict__ w1p, float* __restrict__ scr, int N)
{
  __shared__ float sp[2][64];   // [colhalf][node_local]

  const int tid = threadIdx.x;
  const int w = tid >> 6, l = tid & 63;
  const int colhalf = w & 1, wp = w >> 1;
  const int l15 = l & 15, lg = l >> 4;
  const int node0 = blockIdx.x * 64;

  float b1v[4], w2v[4];
  #pragma unroll
  for (int ct = 0; ct < 4; ++ct) {
    int c = colhalf * 64 + ct * 16 + l15;
    b1v[ct] = b1[c];
    w2v[ct] = W2[c];
  }
  const float b2s = b2p[0];

  #pragma unroll
  for (int t = wp; t < 4; t += 2) {
    int row = node0 + t * 16 + l15;
    if (row >= N) row = N - 1;          // pad rows: discarded at write
    const float* xp = x + (size_t)row * 256 + lg * 8;
    f32x4 acc0 = {0.f,0.f,0.f,0.f}, acc1 = {0.f,0.f,0.f,0.f};
    f32x4 acc2 = {0.f,0.f,0.f,0.f}, acc3 = {0.f,0.f,0.f,0.f};
    #pragma unroll
    for (int kt = 0; kt < 8; ++kt) {
      float4 xa = *(const float4*)(xp + kt * 32);
      float4 xb = *(const float4*)(xp + kt * 32 + 4);
      const s16x8* wb = w1p + (kt * 8 + colhalf * 4) * 64 + l;   // L2-resident
      s16x8 bf0 = wb[0], bf1 = wb[64], bf2 = wb[128], bf3 = wb[192];
      s16x8 a;
      a[0] = f2bf(xa.x); a[1] = f2bf(xa.y); a[2] = f2bf(xa.z); a[3] = f2bf(xa.w);
      a[4] = f2bf(xb.x); a[5] = f2bf(xb.y); a[6] = f2bf(xb.z); a[7] = f2bf(xb.w);
      acc0 = __builtin_amdgcn_mfma_f32_16x16x32_bf16(a, bf0, acc0, 0, 0, 0);
      acc1 = __builtin_amdgcn_mfma_f32_16x16x32_bf16(a, bf1, acc1, 0, 0, 0);
      acc2 = __builtin_amdgcn_mfma_f32_16x16x32_bf16(a, bf2, acc2, 0, 0, 0);
      acc3 = __builtin_amdgcn_mfma_f32_16x16x32_bf16(a, bf3, acc3, 0, 0, 0);
    }
    // h = tanh(acc + b1); partial score = sum h*W2 over this wave's 64 cols.
    // D layout: node-in-tile = 4*lg + r, hidden-col = ct*16 + l15.
    float part[4];
    #pragma unroll
    for (int r = 0; r < 4; ++r) {
      part[r] = colhalf ? 0.f : b2s;
      part[r] += fast_tanh(acc0[r] + b1v[0]) * w2v[0];
      part[r] += fast_tanh(acc1[r] + b1v[1]) * w2v[1];
      part[r] += fast_tanh(acc2[r] + b1v[2]) * w2v[2];
      part[r] += fast_tanh(acc3[r] + b1v[3]) * w2v[3];
    }
    #pragma unroll
    for (int m = 1; m <= 8; m <<= 1) {
      #pragma unroll
      for (int r = 0; r < 4; ++r) part[r] += __shfl_xor(part[r], m, 64);
    }
    if (l15 == 0) {
      #pragma unroll
      for (int r = 0; r < 4; ++r)
        sp[colhalf][t * 16 + lg * 4 + r] = part[r];
    }
  }
  __syncthreads();
  if (tid < 64) {
    int node = node0 + tid;
    if (node < N) scr[node] = sp[0][tid] + sp[1][tid];
  }
}

// Kernel B: per-graph softmax + pooling (R1 phases 2+3). wts holds raw scores
// on entry (written by gate_scores), softmax weights on exit. Blocks iterate
// graphs in REVERSE so early blocks hit the L3-resident tail of x.
__global__ __launch_bounds__(256, 8)
void softmax_pool(const float* __restrict__ x, const int* __restrict__ offs,
                  float* wts, float* __restrict__ pooled, int N)
{
  __shared__ float sc[MAXN];
  __shared__ float sred[8];

  const int g = NGRAPH - 1 - blockIdx.x;   // reverse for L3 tail reuse
  const int tid = threadIdx.x;
  const int w = tid >> 6, l = tid & 63;

  const int s = offs[g];
  const int cnt = min(offs[g + 1] - s, MAXN);   // clamp: never-taken safety net

  if (cnt == 0) {
    pooled[(size_t)g * 256 + tid] = 0.f;   // empty segment -> zeros (ref guard)
    return;
  }

  // ---- softmax over segment scores (deterministic, no atomics) ----
  float lmax = -1e30f;
  for (int i = tid; i < cnt; i += 256) {
    float v = wts[s + i];
    sc[i] = v;
    lmax = fmaxf(lmax, v);
  }
  #pragma unroll
  for (int m = 1; m <= 32; m <<= 1) lmax = fmaxf(lmax, __shfl_xor(lmax, m, 64));
  if (l == 0) sred[w] = lmax;
  __syncthreads();
  const float gmax = fmaxf(fmaxf(sred[0], sred[1]), fmaxf(sred[2], sred[3]));
  float lsum = 0.f;
  for (int i = tid; i < cnt; i += 256) {
    float ev = __expf(sc[i] - gmax);
    sc[i] = ev;
    lsum += ev;
  }
  #pragma unroll
  for (int m = 1; m <= 32; m <<= 1) lsum += __shfl_xor(lsum, m, 64);
  if (l == 0) sred[4 + w] = lsum;
  __syncthreads();
  const float inv = 1.f / (sred[4] + sred[5] + sred[6] + sred[7]);
  for (int i = tid; i < cnt; i += 256) {
    float wt = sc[i] * inv;
    sc[i] = wt;
    wts[s + i] = wt;
  }
  __syncthreads();

  // ---- pooled[g][col] = sum_n w_n * x[s+n][col], col = tid ----
  float pacc = 0.f;
  const float* xg = x + (size_t)s * 256 + tid;
  int n = 0;
  for (; n + 8 <= cnt; n += 8) {
    float wv[8], xv[8];
    #pragma unroll
    for (int u = 0; u < 8; ++u) {
      wv[u] = sc[n + u];
      xv[u] = xg[(size_t)(n + u) * 256];
    }
    #pragma unroll
    for (int u = 0; u < 8; ++u) pacc += wv[u] * xv[u];
  }
  for (; n < cnt; ++n) pacc += sc[n] * xg[(size_t)n * 256];
  pooled[(size_t)g * 256 + tid] = pacc;
}

extern "C" void kernel_launch(void* const* d_in, const int* in_sizes, int n_in,
                              void* d_out, int out_size, void* d_ws, size_t ws_size,
                              hipStream_t stream) {
  const float* x     = (const float*)d_in[0];
  const void*  batch = d_in[1];
  const float* W1    = (const float*)d_in[2];
  const float* b1    = (const float*)d_in[3];
  const float* W2    = (const float*)d_in[4];
  const float* b2    = (const float*)d_in[5];
  const int N = in_sizes[0] / 256;

  float* pooled = (float*)d_out;
  float* wout   = (float*)d_out + (size_t)NGRAPH * 256;  // N floats: raw scores, then weights
  s16x8* w1p    = (s16x8*)d_ws;                       // 64 KB
  int*   offs   = (int*)((char*)d_ws + 64 * 1024);    // 4097 * 4 B

  prepack_w1<<<16, 256, 0, stream>>>(W1, w1p);
  seg_offsets<<<17, 256, 0, stream>>>(batch, offs, N);
  gate_scores<<<(N + 63) / 64, 256, 0, stream>>>(x, b1, W2, b2, w1p, wout, N);
  softmax_pool<<<NGRAPH, 256, 0, stream>>>(x, offs, wout, pooled, N);
}

// Round 6
// 269.589 us; speedup vs baseline: 1.7003x; 1.0972x over previous
//
#include <hip/hip_runtime.h>
#include <hip/hip_bf16.h>

#define NGRAPH 4096

typedef __attribute__((ext_vector_type(8))) short s16x8;
typedef __attribute__((ext_vector_type(4))) float f32x4;

__device__ inline short f2bf(float f) {
  unsigned u = __float_as_uint(f);
  unsigned r = u + 0x7fffu + ((u >> 16) & 1u);
  return (short)(r >> 16);
}

// Prepack W1 (256x128 fp32, row-major) into bf16 MFMA B-fragment order.
// Fragment f = kt*8 + ct (kt,ct in 0..7). Lane l supplies B[k][c] for
// k = kt*32 + (l>>4)*8 + e (e=0..7), c = ct*16 + (l&15).
__global__ void prepack_w1(const float* __restrict__ W1, s16x8* __restrict__ w1p) {
  int t = blockIdx.x * 256 + threadIdx.x;   // 4096 threads total
  int f = t >> 6, l = t & 63;
  int kt = f >> 3, ct = f & 7;
  int k0 = kt * 32 + ((l >> 4) * 8);
  int c  = ct * 16 + (l & 15);
  s16x8 v;
  #pragma unroll
  for (int e = 0; e < 8; ++e) v[e] = f2bf(W1[(k0 + e) * 128 + c]);
  w1p[f * 64 + l] = v;
}

__device__ inline long long getb(const void* b, int i, int is64) {
  if (is64) return ((const long long*)b)[i];
  return (long long)((const int*)b)[i];
}

__device__ inline int lowb(const void* b, int n, long long v, int is64) {
  int lo = 0, hi = n;
  while (lo < hi) {
    int mid = (lo + hi) >> 1;
    if (getb(b, mid, is64) < v) lo = mid + 1; else hi = mid;
  }
  return lo;
}

__device__ inline int batch_is64(const void* batch, int N) {
  // int64 vs int32 materialization probe: an odd 32-bit word index has a zero
  // high word under int64 (values < 2^31), a near-max sorted id under int32.
  int probe = ((N & 1) == 0) ? (N - 1) : (N - 2);
  return (((const int*)batch)[probe] == 0) ? 1 : 0;
}

// One-time: offs[g] = lower_bound(batch, g). 4097 independent searches,
// latency hidden by TLP; batch (2-4 MB) L2/L3-resident after first touches.
__global__ void seg_offsets(const void* __restrict__ batch, int* __restrict__ offs, int N) {
  int g = blockIdx.x * 256 + threadIdx.x;
  const int is64 = batch_is64(batch, N);
  if (g <= NGRAPH) offs[g] = lowb(batch, N, (long long)g, is64);
}

__device__ inline float fast_tanh(float v) {
  v = fminf(fmaxf(v, -15.f), 15.f);
  float e = __expf(2.f * v);
  return __fdividef(e - 1.f, e + 1.f);
}

// Fused kernel: block = 64 nodes, 256 threads (2 wave-pairs x colhalf).
// Phase A: gate scores via MFMA (exactly R5's gate_scores).
// Scores are bounded (|s| <= ||W2||_1 ~ 9), so exp(s) needs NO max-subtraction
// -> no global softmax dependency -> pooling fuses right here, re-reading the
// block's 64 x-rows from L1/L2 (just fetched). Cross-block segment joins via
// atomicAdd on pooled[] and segsum[] (zeroed each call by hipMemsetAsync).
__global__ __launch_bounds__(256, 3)
void gate_pool(const float* __restrict__ x, const int* __restrict__ offs,
               const float* __restrict__ b1, const float* __restrict__ W2,
               const float* __restrict__ b2p, const s16x8* __restrict__ w1p,
               float* __restrict__ pooled, float* __restrict__ expout,
               float* __restrict__ segsum, int N)
{
  __shared__ float sp[2][64];   // [colhalf][node_local] partial scores
  __shared__ float sw[64];      // exp(score) per local row

  const int tid = threadIdx.x;
  const int w = tid >> 6, l = tid & 63;
  const int colhalf = w & 1, wp = w >> 1;
  const int l15 = l & 15, lg = l >> 4;
  const int node0 = blockIdx.x * 64;

  float b1v[4], w2v[4];
  #pragma unroll
  for (int ct = 0; ct < 4; ++ct) {
    int c = colhalf * 64 + ct * 16 + l15;
    b1v[ct] = b1[c];
    w2v[ct] = W2[c];
  }
  const float b2s = b2p[0];

  // ---- Phase A: MFMA gate scores (16-node tiles; wave-pair per tile) ----
  #pragma unroll
  for (int t = wp; t < 4; t += 2) {
    int row = node0 + t * 16 + l15;
    if (row >= N) row = N - 1;          // pad rows: discarded at write
    const float* xp = x + (size_t)row * 256 + lg * 8;
    f32x4 acc0 = {0.f,0.f,0.f,0.f}, acc1 = {0.f,0.f,0.f,0.f};
    f32x4 acc2 = {0.f,0.f,0.f,0.f}, acc3 = {0.f,0.f,0.f,0.f};
    #pragma unroll
    for (int kt = 0; kt < 8; ++kt) {
      float4 xa = *(const float4*)(xp + kt * 32);
      float4 xb = *(const float4*)(xp + kt * 32 + 4);
      const s16x8* wb = w1p + (kt * 8 + colhalf * 4) * 64 + l;   // L2-resident
      s16x8 bf0 = wb[0], bf1 = wb[64], bf2 = wb[128], bf3 = wb[192];
      s16x8 a;
      a[0] = f2bf(xa.x); a[1] = f2bf(xa.y); a[2] = f2bf(xa.z); a[3] = f2bf(xa.w);
      a[4] = f2bf(xb.x); a[5] = f2bf(xb.y); a[6] = f2bf(xb.z); a[7] = f2bf(xb.w);
      acc0 = __builtin_amdgcn_mfma_f32_16x16x32_bf16(a, bf0, acc0, 0, 0, 0);
      acc1 = __builtin_amdgcn_mfma_f32_16x16x32_bf16(a, bf1, acc1, 0, 0, 0);
      acc2 = __builtin_amdgcn_mfma_f32_16x16x32_bf16(a, bf2, acc2, 0, 0, 0);
      acc3 = __builtin_amdgcn_mfma_f32_16x16x32_bf16(a, bf3, acc3, 0, 0, 0);
    }
    // h = tanh(acc + b1); partial score = sum h*W2 over this wave's 64 cols.
    // D layout: node-in-tile = 4*lg + r, hidden-col = ct*16 + l15.
    float part[4];
    #pragma unroll
    for (int r = 0; r < 4; ++r) {
      part[r] = colhalf ? 0.f : b2s;
      part[r] += fast_tanh(acc0[r] + b1v[0]) * w2v[0];
      part[r] += fast_tanh(acc1[r] + b1v[1]) * w2v[1];
      part[r] += fast_tanh(acc2[r] + b1v[2]) * w2v[2];
      part[r] += fast_tanh(acc3[r] + b1v[3]) * w2v[3];
    }
    #pragma unroll
    for (int m = 1; m <= 8; m <<= 1) {
      #pragma unroll
      for (int r = 0; r < 4; ++r) part[r] += __shfl_xor(part[r], m, 64);
    }
    if (l15 == 0) {
      #pragma unroll
      for (int r = 0; r < 4; ++r)
        sp[colhalf][t * 16 + lg * 4 + r] = part[r];
    }
  }
  __syncthreads();

  // combine halves, exponentiate (no max needed: |score| <= ~9), store
  if (tid < 64) {
    int node = node0 + tid;
    float e = 0.f;
    if (node < N) {
      e = __expf(sp[0][tid] + sp[1][tid]);
      expout[node] = e;                 // unnormalized weight, fixed in finalize
    }
    sw[tid] = e;
  }
  __syncthreads();

  // ---- Phase B: pooling, col = tid, rows re-read from L1/L2 (hot) ----
  const int nmax = min(64, N - node0);
  // g: graph containing node0 (upper_bound on offs)
  int g;
  {
    int lo = 0, hi = NGRAPH - 1;
    while (lo < hi) {
      int mid = (lo + hi) >> 1;
      if (offs[mid + 1] <= node0) lo = mid + 1; else hi = mid;
    }
    g = lo;
  }
  const float* xg = x + (size_t)node0 * 256 + tid;
  int r = 0;
  int nb = offs[g + 1];
  while (r < nmax) {
    const int rend = min(nb - node0, nmax);
    float pacc = 0.f, wsum = 0.f;
    for (; r + 8 <= rend; r += 8) {
      float xv[8];
      #pragma unroll
      for (int u = 0; u < 8; ++u) xv[u] = xg[(size_t)(r + u) * 256];
      #pragma unroll
      for (int u = 0; u < 8; ++u) {
        float wv = sw[r + u];
        pacc += wv * xv[u];
        wsum += wv;
      }
    }
    for (; r < rend; ++r) {
      float wv = sw[r];
      pacc += wv * xg[(size_t)r * 256];
      wsum += wv;
    }
    if (wsum > 0.f) {
      atomicAdd(&pooled[(size_t)g * 256 + tid], pacc);
      if (tid == 0) atomicAdd(&segsum[g], wsum);
    }
    if (rend >= nmax) break;
    ++g;
    nb = offs[g + 1];
  }
}

// Finalize: pooled /= segsum (0 for empty graphs), weights = exp/segsum[batch].
__global__ void finalize(float* __restrict__ pooled, float* __restrict__ wts,
                         const float* __restrict__ segsum,
                         const void* __restrict__ batch, int N)
{
  int f = blockIdx.x * 256 + threadIdx.x;
  if (f < NGRAPH * 256) {
    int g = f >> 8;
    float s = segsum[g];
    pooled[f] = (s > 0.f) ? pooled[f] / s : 0.f;
  } else {
    int n = f - NGRAPH * 256;
    if (n < N) {
      const int is64 = batch_is64(batch, N);
      int g = (int)getb(batch, n, is64);
      wts[n] = wts[n] / segsum[g];
    }
  }
}

extern "C" void kernel_launch(void* const* d_in, const int* in_sizes, int n_in,
                              void* d_out, int out_size, void* d_ws, size_t ws_size,
                              hipStream_t stream) {
  const float* x     = (const float*)d_in[0];
  const void*  batch = d_in[1];
  const float* W1    = (const float*)d_in[2];
  const float* b1    = (const float*)d_in[3];
  const float* W2    = (const float*)d_in[4];
  const float* b2    = (const float*)d_in[5];
  const int N = in_sizes[0] / 256;

  float* pooled = (float*)d_out;                          // 4096*256
  float* wout   = (float*)d_out + (size_t)NGRAPH * 256;   // N: exp(s), then weights
  s16x8* w1p    = (s16x8*)d_ws;                           // 64 KB
  int*   offs   = (int*)((char*)d_ws + 64 * 1024);        // 4097 * 4 B
  float* segsum = (float*)((char*)d_ws + 96 * 1024);      // 4096 * 4 B

  // Atomic accumulators must start at zero EVERY call (graph replays included).
  hipMemsetAsync(pooled, 0, (size_t)NGRAPH * 256 * sizeof(float), stream);
  hipMemsetAsync(segsum, 0, (size_t)NGRAPH * sizeof(float), stream);

  prepack_w1<<<16, 256, 0, stream>>>(W1, w1p);
  seg_offsets<<<17, 256, 0, stream>>>(batch, offs, N);
  gate_pool<<<(N + 63) / 64, 256, 0, stream>>>(x, offs, b1, W2, b2, w1p,
                                               pooled, wout, segsum, N);
  const int tot = NGRAPH * 256 + N;
  finalize<<<(tot + 255) / 256, 256, 0, stream>>>(pooled, wout, segsum, batch, N);
}

// Round 7
// 232.656 us; speedup vs baseline: 1.9702x; 1.1587x over previous
//
#include <hip/hip_runtime.h>
#include <hip/hip_bf16.h>

#define NGRAPH 4096

typedef __attribute__((ext_vector_type(8))) short s16x8;
typedef __attribute__((ext_vector_type(4))) float f32x4;

__device__ inline short f2bf(float f) {
  unsigned u = __float_as_uint(f);
  unsigned r = u + 0x7fffu + ((u >> 16) & 1u);
  return (short)(r >> 16);
}

// Prepack W1 (256x128 fp32, row-major) into bf16 MFMA B-fragment order.
// Fragment f = kt*8 + ct (kt,ct in 0..7). Lane l supplies B[k][c] for
// k = kt*32 + (l>>4)*8 + e (e=0..7), c = ct*16 + (l&15).
__global__ void prepack_w1(const float* __restrict__ W1, s16x8* __restrict__ w1p) {
  int t = blockIdx.x * 256 + threadIdx.x;   // 4096 threads total
  int f = t >> 6, l = t & 63;
  int kt = f >> 3, ct = f & 7;
  int k0 = kt * 32 + ((l >> 4) * 8);
  int c  = ct * 16 + (l & 15);
  s16x8 v;
  #pragma unroll
  for (int e = 0; e < 8; ++e) v[e] = f2bf(W1[(k0 + e) * 128 + c]);
  w1p[f * 64 + l] = v;
}

__device__ inline long long getb(const void* b, int i, int is64) {
  if (is64) return ((const long long*)b)[i];
  return (long long)((const int*)b)[i];
}

__device__ inline int lowb(const void* b, int n, long long v, int is64) {
  int lo = 0, hi = n;
  while (lo < hi) {
    int mid = (lo + hi) >> 1;
    if (getb(b, mid, is64) < v) lo = mid + 1; else hi = mid;
  }
  return lo;
}

__device__ inline int batch_is64(const void* batch, int N) {
  // int64 vs int32 materialization probe: an odd 32-bit word index has a zero
  // high word under int64 (values < 2^31), a near-max sorted id under int32.
  int probe = ((N & 1) == 0) ? (N - 1) : (N - 2);
  return (((const int*)batch)[probe] == 0) ? 1 : 0;
}

// One-time: offs[g] = lower_bound(batch, g). 4097 independent searches,
// latency hidden by TLP; batch (2-4 MB) L2/L3-resident after first touches.
__global__ void seg_offsets(const void* __restrict__ batch, int* __restrict__ offs, int N) {
  int g = blockIdx.x * 256 + threadIdx.x;
  const int is64 = batch_is64(batch, N);
  if (g <= NGRAPH) offs[g] = lowb(batch, N, (long long)g, is64);
}

__device__ inline float fast_tanh(float v) {
  v = fminf(fmaxf(v, -15.f), 15.f);
  float e = __expf(2.f * v);
  return __fdividef(e - 1.f, e + 1.f);
}

// Fused kernel: block = 64 nodes, 256 threads (2 wave-pairs x colhalf).
// Phase A: gate scores via MFMA. Each wave-pair now processes its TWO 16-node
// tiles SIMULTANEOUSLY (dual A-fragments + dual accumulators, shared
// B-fragments): doubles loads-in-flight per wave, halves w1p L2 traffic.
// Scores bounded (|s| <= ||W2||_1 ~ 9) -> exp(s) safe without max-subtraction
// -> pooling fuses here, re-reading the block's 64 x-rows from L1/L2.
// Cross-block segment joins via atomicAdd (buffers zeroed every call).
__global__ __launch_bounds__(256, 3)
void gate_pool(const float* __restrict__ x, const int* __restrict__ offs,
               const float* __restrict__ b1, const float* __restrict__ W2,
               const float* __restrict__ b2p, const s16x8* __restrict__ w1p,
               float* __restrict__ pooled, float* __restrict__ expout,
               float* __restrict__ segsum, int N)
{
  __shared__ float sp[2][64];   // [colhalf][node_local] partial scores
  __shared__ float sw[64];      // exp(score) per local row

  const int tid = threadIdx.x;
  const int w = tid >> 6, l = tid & 63;
  const int colhalf = w & 1, wp = w >> 1;
  const int l15 = l & 15, lg = l >> 4;
  const int node0 = blockIdx.x * 64;

  float b1v[4], w2v[4];
  #pragma unroll
  for (int ct = 0; ct < 4; ++ct) {
    int c = colhalf * 64 + ct * 16 + l15;
    b1v[ct] = b1[c];
    w2v[ct] = W2[c];
  }
  const float b2s = b2p[0];

  // ---- Phase A: MFMA gate scores; wave-pair wp owns nodes wp*32..wp*32+31
  //      as two concurrent 16-node tiles (A and B). ----
  {
    int rowA = node0 + wp * 32 + l15;
    int rowB = rowA + 16;
    if (rowA >= N) rowA = N - 1;        // pad rows: discarded at write
    if (rowB >= N) rowB = N - 1;
    const float* xpA = x + (size_t)rowA * 256 + lg * 8;
    const float* xpB = x + (size_t)rowB * 256 + lg * 8;

    f32x4 accA0 = {0.f,0.f,0.f,0.f}, accA1 = {0.f,0.f,0.f,0.f};
    f32x4 accA2 = {0.f,0.f,0.f,0.f}, accA3 = {0.f,0.f,0.f,0.f};
    f32x4 accB0 = {0.f,0.f,0.f,0.f}, accB1 = {0.f,0.f,0.f,0.f};
    f32x4 accB2 = {0.f,0.f,0.f,0.f}, accB3 = {0.f,0.f,0.f,0.f};
    #pragma unroll
    for (int kt = 0; kt < 8; ++kt) {
      float4 xa0 = *(const float4*)(xpA + kt * 32);
      float4 xb0 = *(const float4*)(xpA + kt * 32 + 4);
      float4 xa1 = *(const float4*)(xpB + kt * 32);
      float4 xb1 = *(const float4*)(xpB + kt * 32 + 4);
      const s16x8* wb = w1p + (kt * 8 + colhalf * 4) * 64 + l;   // L2-resident
      s16x8 bf0 = wb[0], bf1 = wb[64], bf2 = wb[128], bf3 = wb[192];
      s16x8 a0, a1;
      a0[0] = f2bf(xa0.x); a0[1] = f2bf(xa0.y); a0[2] = f2bf(xa0.z); a0[3] = f2bf(xa0.w);
      a0[4] = f2bf(xb0.x); a0[5] = f2bf(xb0.y); a0[6] = f2bf(xb0.z); a0[7] = f2bf(xb0.w);
      a1[0] = f2bf(xa1.x); a1[1] = f2bf(xa1.y); a1[2] = f2bf(xa1.z); a1[3] = f2bf(xa1.w);
      a1[4] = f2bf(xb1.x); a1[5] = f2bf(xb1.y); a1[6] = f2bf(xb1.z); a1[7] = f2bf(xb1.w);
      accA0 = __builtin_amdgcn_mfma_f32_16x16x32_bf16(a0, bf0, accA0, 0, 0, 0);
      accA1 = __builtin_amdgcn_mfma_f32_16x16x32_bf16(a0, bf1, accA1, 0, 0, 0);
      accA2 = __builtin_amdgcn_mfma_f32_16x16x32_bf16(a0, bf2, accA2, 0, 0, 0);
      accA3 = __builtin_amdgcn_mfma_f32_16x16x32_bf16(a0, bf3, accA3, 0, 0, 0);
      accB0 = __builtin_amdgcn_mfma_f32_16x16x32_bf16(a1, bf0, accB0, 0, 0, 0);
      accB1 = __builtin_amdgcn_mfma_f32_16x16x32_bf16(a1, bf1, accB1, 0, 0, 0);
      accB2 = __builtin_amdgcn_mfma_f32_16x16x32_bf16(a1, bf2, accB2, 0, 0, 0);
      accB3 = __builtin_amdgcn_mfma_f32_16x16x32_bf16(a1, bf3, accB3, 0, 0, 0);
    }
    // h = tanh(acc + b1); partial score = sum h*W2 over this wave's 64 cols.
    // D layout: node-in-tile = 4*lg + r, hidden-col = ct*16 + l15.
    float partA[4], partB[4];
    #pragma unroll
    for (int r = 0; r < 4; ++r) {
      float init = colhalf ? 0.f : b2s;
      partA[r] = init
        + fast_tanh(accA0[r] + b1v[0]) * w2v[0]
        + fast_tanh(accA1[r] + b1v[1]) * w2v[1]
        + fast_tanh(accA2[r] + b1v[2]) * w2v[2]
        + fast_tanh(accA3[r] + b1v[3]) * w2v[3];
      partB[r] = init
        + fast_tanh(accB0[r] + b1v[0]) * w2v[0]
        + fast_tanh(accB1[r] + b1v[1]) * w2v[1]
        + fast_tanh(accB2[r] + b1v[2]) * w2v[2]
        + fast_tanh(accB3[r] + b1v[3]) * w2v[3];
    }
    #pragma unroll
    for (int m = 1; m <= 8; m <<= 1) {
      #pragma unroll
      for (int r = 0; r < 4; ++r) {
        partA[r] += __shfl_xor(partA[r], m, 64);
        partB[r] += __shfl_xor(partB[r], m, 64);
      }
    }
    if (l15 == 0) {
      #pragma unroll
      for (int r = 0; r < 4; ++r) {
        sp[colhalf][wp * 32      + lg * 4 + r] = partA[r];
        sp[colhalf][wp * 32 + 16 + lg * 4 + r] = partB[r];
      }
    }
  }
  __syncthreads();

  // combine halves, exponentiate (no max needed: |score| <= ~9), store
  if (tid < 64) {
    int node = node0 + tid;
    float e = 0.f;
    if (node < N) {
      e = __expf(sp[0][tid] + sp[1][tid]);
      expout[node] = e;                 // unnormalized weight, fixed in finalize
    }
    sw[tid] = e;
  }
  __syncthreads();

  // ---- Phase B: pooling, col = tid, rows re-read from L1/L2 (hot) ----
  const int nmax = min(64, N - node0);
  // g: graph containing node0 (upper_bound on offs)
  int g;
  {
    int lo = 0, hi = NGRAPH - 1;
    while (lo < hi) {
      int mid = (lo + hi) >> 1;
      if (offs[mid + 1] <= node0) lo = mid + 1; else hi = mid;
    }
    g = lo;
  }
  const float* xg = x + (size_t)node0 * 256 + tid;
  int r = 0;
  int nb = offs[g + 1];
  while (r < nmax) {
    const int rend = min(nb - node0, nmax);
    float pacc = 0.f, wsum = 0.f;
    for (; r + 8 <= rend; r += 8) {
      float xv[8];
      #pragma unroll
      for (int u = 0; u < 8; ++u) xv[u] = xg[(size_t)(r + u) * 256];
      #pragma unroll
      for (int u = 0; u < 8; ++u) {
        float wv = sw[r + u];
        pacc += wv * xv[u];
        wsum += wv;
      }
    }
    for (; r < rend; ++r) {
      float wv = sw[r];
      pacc += wv * xg[(size_t)r * 256];
      wsum += wv;
    }
    if (wsum > 0.f) {
      atomicAdd(&pooled[(size_t)g * 256 + tid], pacc);
      if (tid == 0) atomicAdd(&segsum[g], wsum);
    }
    if (rend >= nmax) break;
    ++g;
    nb = offs[g + 1];
  }
}

// Finalize: pooled /= segsum (0 for empty graphs), weights = exp/segsum[batch].
__global__ void finalize(float* __restrict__ pooled, float* __restrict__ wts,
                         const float* __restrict__ segsum,
                         const void* __restrict__ batch, int N)
{
  int f = blockIdx.x * 256 + threadIdx.x;
  if (f < NGRAPH * 256) {
    int g = f >> 8;
    float s = segsum[g];
    pooled[f] = (s > 0.f) ? pooled[f] / s : 0.f;
  } else {
    int n = f - NGRAPH * 256;
    if (n < N) {
      const int is64 = batch_is64(batch, N);
      int g = (int)getb(batch, n, is64);
      wts[n] = wts[n] / segsum[g];
    }
  }
}

extern "C" void kernel_launch(void* const* d_in, const int* in_sizes, int n_in,
                              void* d_out, int out_size, void* d_ws, size_t ws_size,
                              hipStream_t stream) {
  const float* x     = (const float*)d_in[0];
  const void*  batch = d_in[1];
  const float* W1    = (const float*)d_in[2];
  const float* b1    = (const float*)d_in[3];
  const float* W2    = (const float*)d_in[4];
  const float* b2    = (const float*)d_in[5];
  const int N = in_sizes[0] / 256;

  float* pooled = (float*)d_out;                          // 4096*256
  float* wout   = (float*)d_out + (size_t)NGRAPH * 256;   // N: exp(s), then weights
  s16x8* w1p    = (s16x8*)d_ws;                           // 64 KB
  int*   offs   = (int*)((char*)d_ws + 64 * 1024);        // 4097 * 4 B
  float* segsum = (float*)((char*)d_ws + 96 * 1024);      // 4096 * 4 B

  // Atomic accumulators must start at zero EVERY call (graph replays included).
  hipMemsetAsync(pooled, 0, (size_t)NGRAPH * 256 * sizeof(float), stream);
  hipMemsetAsync(segsum, 0, (size_t)NGRAPH * sizeof(float), stream);

  prepack_w1<<<16, 256, 0, stream>>>(W1, w1p);
  seg_offsets<<<17, 256, 0, stream>>>(batch, offs, N);
  gate_pool<<<(N + 63) / 64, 256, 0, stream>>>(x, offs, b1, W2, b2, w1p,
                                               pooled, wout, segsum, N);
  const int tot = NGRAPH * 256 + N;
  finalize<<<(tot + 255) / 256, 256, 0, stream>>>(pooled, wout, segsum, batch, N);
}

// Round 8
// 193.456 us; speedup vs baseline: 2.3694x; 1.2026x over previous
//
#include <hip/hip_runtime.h>
#include <hip/hip_bf16.h>

#define NGRAPH 4096

typedef __attribute__((ext_vector_type(8))) short s16x8;
typedef __attribute__((ext_vector_type(4))) float f32x4;
typedef unsigned int u32;

__device__ inline short f2bf(float f) {
  unsigned u = __float_as_uint(f);
  unsigned r = u + 0x7fffu + ((u >> 16) & 1u);
  return (short)(r >> 16);
}

// Prepack W1 (256x128 fp32, row-major) into bf16 MFMA B-fragment order.
// Fragment f = kt*8 + ct (kt,ct in 0..7). Lane l supplies B[k][c] for
// k = kt*32 + (l>>4)*8 + e (e=0..7), c = ct*16 + (l&15).
__global__ void prepack_w1(const float* __restrict__ W1, s16x8* __restrict__ w1p) {
  int t = blockIdx.x * 256 + threadIdx.x;   // 4096 threads total
  int f = t >> 6, l = t & 63;
  int kt = f >> 3, ct = f & 7;
  int k0 = kt * 32 + ((l >> 4) * 8);
  int c  = ct * 16 + (l & 15);
  s16x8 v;
  #pragma unroll
  for (int e = 0; e < 8; ++e) v[e] = f2bf(W1[(k0 + e) * 128 + c]);
  w1p[f * 64 + l] = v;
}

__device__ inline long long getb(const void* b, int i, int is64) {
  if (is64) return ((const long long*)b)[i];
  return (long long)((const int*)b)[i];
}

__device__ inline int lowb(const void* b, int n, long long v, int is64) {
  int lo = 0, hi = n;
  while (lo < hi) {
    int mid = (lo + hi) >> 1;
    if (getb(b, mid, is64) < v) lo = mid + 1; else hi = mid;
  }
  return lo;
}

__device__ inline int batch_is64(const void* batch, int N) {
  // int64 vs int32 materialization probe: an odd 32-bit word index has a zero
  // high word under int64 (values < 2^31), a near-max sorted id under int32.
  int probe = ((N & 1) == 0) ? (N - 1) : (N - 2);
  return (((const int*)batch)[probe] == 0) ? 1 : 0;
}

// One-time: offs[g] = lower_bound(batch, g). 4097 independent searches,
// latency hidden by TLP; batch (2-4 MB) L2/L3-resident after first touches.
__global__ void seg_offsets(const void* __restrict__ batch, int* __restrict__ offs, int N) {
  int g = blockIdx.x * 256 + threadIdx.x;
  const int is64 = batch_is64(batch, N);
  if (g <= NGRAPH) offs[g] = lowb(batch, N, (long long)g, is64);
}

__device__ inline float fast_tanh(float v) {
  v = fminf(fmaxf(v, -15.f), 15.f);
  float e = __expf(2.f * v);
  return __fdividef(e - 1.f, e + 1.f);
}

__device__ inline void dma16(const float* src, char* ldsdst) {
  __builtin_amdgcn_global_load_lds(
      (const __attribute__((address_space(1))) u32*)src,
      (__attribute__((address_space(3))) u32*)ldsdst,
      16, 0, 0);   // 16 B/lane: lane l -> ldsdst + l*16
}

// Fused kernel: block = 64 nodes, 256 threads. The x-tile (64 rows x 1 KB)
// is DMA'd ONCE into LDS via global_load_lds (async; per-lane source chunk
// pre-swizzled cc^(row&7) so LDS reads are bank-spread), then:
//  Phase A: MFMA gate scores read A-fragments from LDS (no global x loads;
//           both colhalf waves share the same LDS rows for free).
//  Phase B: pooling reads columns from LDS (no L2 re-read).
// HBM traffic = exactly 64 KB/block. 2 blocks/CU: one block's DMA overlaps
// the other's compute, keeping HBM saturated.
// Scores bounded (|s| <= ||W2||_1 + |b2| ~ 9) -> exp without max-subtraction.
// Cross-block segment joins via atomicAdd (buffers zeroed every call).
__global__ __launch_bounds__(256, 2)
void gate_pool(const float* __restrict__ x, const int* __restrict__ offs,
               const float* __restrict__ b1, const float* __restrict__ W2,
               const float* __restrict__ b2p, const s16x8* __restrict__ w1p,
               float* __restrict__ pooled, float* __restrict__ expout,
               float* __restrict__ segsum, int N)
{
  __shared__ __align__(16) char tile[64 * 1024];  // [row][swizzled 16B chunks]
  __shared__ float sp[2][64];   // [colhalf][node_local] partial scores
  __shared__ float sw[64];      // exp(score) per local row

  const int tid = threadIdx.x;
  const int w = tid >> 6, l = tid & 63;
  const int colhalf = w & 1, wp = w >> 1;
  const int l15 = l & 15, lg = l >> 4;
  const int node0 = blockIdx.x * 64;

  // ---- async DMA: wave w stages rows w, w+4, ..., w+60 (1 KB each) ----
  #pragma unroll
  for (int i = 0; i < 16; ++i) {
    const int r = i * 4 + w;                 // local row (wave-uniform)
    int grow = node0 + r;
    if (grow >= N) grow = N - 1;             // pad rows: discarded later
    // lane l fills LDS chunk l of row r; source chunk = l ^ (r&7) (swizzle)
    const float* src = x + (size_t)grow * 256 + ((l ^ (r & 7)) << 2);
    dma16(src, tile + r * 1024);
  }

  float b1v[4], w2v[4];
  #pragma unroll
  for (int ct = 0; ct < 4; ++ct) {
    int c = colhalf * 64 + ct * 16 + l15;
    b1v[ct] = b1[c];
    w2v[ct] = W2[c];
  }
  const float b2s = b2p[0];

  __syncthreads();   // compiler drains vmcnt(0) before barrier -> tile ready

  // ---- Phase A: MFMA gate scores; wave-pair wp owns local rows wp*32..+31
  //      as two concurrent 16-node tiles (A and B), read from LDS. ----
  {
    const int r0 = wp * 32 + l15;            // tile A row
    const int r1 = r0 + 16;                  // tile B row
    const char* p0 = tile + r0 * 1024;
    const char* p1 = tile + r1 * 1024;
    const int s0 = (r0 & 7), s1 = (r1 & 7);

    f32x4 accA0 = {0.f,0.f,0.f,0.f}, accA1 = {0.f,0.f,0.f,0.f};
    f32x4 accA2 = {0.f,0.f,0.f,0.f}, accA3 = {0.f,0.f,0.f,0.f};
    f32x4 accB0 = {0.f,0.f,0.f,0.f}, accB1 = {0.f,0.f,0.f,0.f};
    f32x4 accB2 = {0.f,0.f,0.f,0.f}, accB3 = {0.f,0.f,0.f,0.f};
    #pragma unroll
    for (int kt = 0; kt < 8; ++kt) {
      const int cc = kt * 8 + lg * 2;        // 16B-chunk index of 8-float slab
      float4 xa0 = *(const float4*)(p0 + (((cc    ) ^ s0) << 4));
      float4 xb0 = *(const float4*)(p0 + (((cc + 1) ^ s0) << 4));
      float4 xa1 = *(const float4*)(p1 + (((cc    ) ^ s1) << 4));
      float4 xb1 = *(const float4*)(p1 + (((cc + 1) ^ s1) << 4));
      const s16x8* wb = w1p + (kt * 8 + colhalf * 4) * 64 + l;   // L2-resident
      s16x8 bf0 = wb[0], bf1 = wb[64], bf2 = wb[128], bf3 = wb[192];
      s16x8 a0, a1;
      a0[0] = f2bf(xa0.x); a0[1] = f2bf(xa0.y); a0[2] = f2bf(xa0.z); a0[3] = f2bf(xa0.w);
      a0[4] = f2bf(xb0.x); a0[5] = f2bf(xb0.y); a0[6] = f2bf(xb0.z); a0[7] = f2bf(xb0.w);
      a1[0] = f2bf(xa1.x); a1[1] = f2bf(xa1.y); a1[2] = f2bf(xa1.z); a1[3] = f2bf(xa1.w);
      a1[4] = f2bf(xb1.x); a1[5] = f2bf(xb1.y); a1[6] = f2bf(xb1.z); a1[7] = f2bf(xb1.w);
      accA0 = __builtin_amdgcn_mfma_f32_16x16x32_bf16(a0, bf0, accA0, 0, 0, 0);
      accA1 = __builtin_amdgcn_mfma_f32_16x16x32_bf16(a0, bf1, accA1, 0, 0, 0);
      accA2 = __builtin_amdgcn_mfma_f32_16x16x32_bf16(a0, bf2, accA2, 0, 0, 0);
      accA3 = __builtin_amdgcn_mfma_f32_16x16x32_bf16(a0, bf3, accA3, 0, 0, 0);
      accB0 = __builtin_amdgcn_mfma_f32_16x16x32_bf16(a1, bf0, accB0, 0, 0, 0);
      accB1 = __builtin_amdgcn_mfma_f32_16x16x32_bf16(a1, bf1, accB1, 0, 0, 0);
      accB2 = __builtin_amdgcn_mfma_f32_16x16x32_bf16(a1, bf2, accB2, 0, 0, 0);
      accB3 = __builtin_amdgcn_mfma_f32_16x16x32_bf16(a1, bf3, accB3, 0, 0, 0);
    }
    // h = tanh(acc + b1); partial score = sum h*W2 over this wave's 64 cols.
    // D layout: node-in-tile = 4*lg + r, hidden-col = ct*16 + l15.
    float partA[4], partB[4];
    #pragma unroll
    for (int r = 0; r < 4; ++r) {
      float init = colhalf ? 0.f : b2s;
      partA[r] = init
        + fast_tanh(accA0[r] + b1v[0]) * w2v[0]
        + fast_tanh(accA1[r] + b1v[1]) * w2v[1]
        + fast_tanh(accA2[r] + b1v[2]) * w2v[2]
        + fast_tanh(accA3[r] + b1v[3]) * w2v[3];
      partB[r] = init
        + fast_tanh(accB0[r] + b1v[0]) * w2v[0]
        + fast_tanh(accB1[r] + b1v[1]) * w2v[1]
        + fast_tanh(accB2[r] + b1v[2]) * w2v[2]
        + fast_tanh(accB3[r] + b1v[3]) * w2v[3];
    }
    #pragma unroll
    for (int m = 1; m <= 8; m <<= 1) {
      #pragma unroll
      for (int r = 0; r < 4; ++r) {
        partA[r] += __shfl_xor(partA[r], m, 64);
        partB[r] += __shfl_xor(partB[r], m, 64);
      }
    }
    if (l15 == 0) {
      #pragma unroll
      for (int r = 0; r < 4; ++r) {
        sp[colhalf][wp * 32      + lg * 4 + r] = partA[r];
        sp[colhalf][wp * 32 + 16 + lg * 4 + r] = partB[r];
      }
    }
  }
  __syncthreads();

  // combine halves, exponentiate (no max needed: |score| <= ~9), store
  if (tid < 64) {
    int node = node0 + tid;
    float e = 0.f;
    if (node < N) {
      e = __expf(sp[0][tid] + sp[1][tid]);
      expout[node] = e;                 // unnormalized weight, fixed in finalize
    }
    sw[tid] = e;
  }
  __syncthreads();

  // ---- Phase B: pooling from LDS, col = tid ----
  const int nmax = min(64, N - node0);
  // g: graph containing node0 (upper_bound on offs)
  int g;
  {
    int lo = 0, hi = NGRAPH - 1;
    while (lo < hi) {
      int mid = (lo + hi) >> 1;
      if (offs[mid + 1] <= node0) lo = mid + 1; else hi = mid;
    }
    g = lo;
  }
  const int ccb = tid >> 2, cib = (tid & 3) << 2;   // chunk + in-chunk byte
  int r = 0;
  int nb = offs[g + 1];
  while (r < nmax) {
    const int rend = min(nb - node0, nmax);
    float pacc = 0.f, wsum = 0.f;
    for (; r + 8 <= rend; r += 8) {
      float xv[8], wv[8];
      #pragma unroll
      for (int u = 0; u < 8; ++u) {
        const int rr = r + u;
        xv[u] = *(const float*)(tile + rr * 1024 + (((ccb ^ (rr & 7)) << 4) | cib));
        wv[u] = sw[rr];
      }
      #pragma unroll
      for (int u = 0; u < 8; ++u) {
        pacc += wv[u] * xv[u];
        wsum += wv[u];
      }
    }
    for (; r < rend; ++r) {
      float wv = sw[r];
      pacc += wv * *(const float*)(tile + r * 1024 + (((ccb ^ (r & 7)) << 4) | cib));
      wsum += wv;
    }
    if (wsum > 0.f) {
      atomicAdd(&pooled[(size_t)g * 256 + tid], pacc);
      if (tid == 0) atomicAdd(&segsum[g], wsum);
    }
    if (rend >= nmax) break;
    ++g;
    nb = offs[g + 1];
  }
}

// Finalize: pooled /= segsum (0 for empty graphs), weights = exp/segsum[batch].
__global__ void finalize(float* __restrict__ pooled, float* __restrict__ wts,
                         const float* __restrict__ segsum,
                         const void* __restrict__ batch, int N)
{
  int f = blockIdx.x * 256 + threadIdx.x;
  if (f < NGRAPH * 256) {
    int g = f >> 8;
    float s = segsum[g];
    pooled[f] = (s > 0.f) ? pooled[f] / s : 0.f;
  } else {
    int n = f - NGRAPH * 256;
    if (n < N) {
      const int is64 = batch_is64(batch, N);
      int g = (int)getb(batch, n, is64);
      wts[n] = wts[n] / segsum[g];
    }
  }
}

extern "C" void kernel_launch(void* const* d_in, const int* in_sizes, int n_in,
                              void* d_out, int out_size, void* d_ws, size_t ws_size,
                              hipStream_t stream) {
  const float* x     = (const float*)d_in[0];
  const void*  batch = d_in[1];
  const float* W1    = (const float*)d_in[2];
  const float* b1    = (const float*)d_in[3];
  const float* W2    = (const float*)d_in[4];
  const float* b2    = (const float*)d_in[5];
  const int N = in_sizes[0] / 256;

  float* pooled = (float*)d_out;                          // 4096*256
  float* wout   = (float*)d_out + (size_t)NGRAPH * 256;   // N: exp(s), then weights
  s16x8* w1p    = (s16x8*)d_ws;                           // 64 KB
  int*   offs   = (int*)((char*)d_ws + 64 * 1024);        // 4097 * 4 B
  float* segsum = (float*)((char*)d_ws + 96 * 1024);      // 4096 * 4 B

  // Atomic accumulators must start at zero EVERY call (graph replays included).
  hipMemsetAsync(pooled, 0, (size_t)NGRAPH * 256 * sizeof(float), stream);
  hipMemsetAsync(segsum, 0, (size_t)NGRAPH * sizeof(float), stream);

  prepack_w1<<<16, 256, 0, stream>>>(W1, w1p);
  seg_offsets<<<17, 256, 0, stream>>>(batch, offs, N);
  gate_pool<<<(N + 63) / 64, 256, 0, stream>>>(x, offs, b1, W2, b2, w1p,
                                               pooled, wout, segsum, N);
  const int tot = NGRAPH * 256 + N;
  finalize<<<(tot + 255) / 256, 256, 0, stream>>>(pooled, wout, segsum, batch, N);
}